// Round 19
// baseline (45.733 us; speedup 1.0000x reference)
//
#include <hip/hip_runtime.h>

#define BB 2
#define TT 512
#define HH 256
#define NBT (BB * TT)          // 1024

#define C2LOG2E 2.8853900817779268f   // 2*log2(e): exp(2x)=2^(C*x)
#define LOG2E   1.4426950408889634f

typedef __attribute__((ext_vector_type(8))) short short8;
typedef __attribute__((ext_vector_type(4))) float f32x4;

__device__ __forceinline__ unsigned short f2bf(float f) {   // RNE float->bf16
    unsigned u = __float_as_uint(f);
    unsigned r = u + 0x7fffu + ((u >> 16) & 1u);
    return (unsigned short)(r >> 16);
}
__device__ __forceinline__ float bflo(unsigned u) { return __uint_as_float(u << 16); }
__device__ __forceinline__ float bfhi(unsigned u) { return __uint_as_float(u & 0xffff0000u); }

// load 8 consecutive fp32 and convert to a bf16 MFMA fragment
__device__ __forceinline__ short8 load_cvt8(const float* __restrict__ p) {
    float4 x0 = *reinterpret_cast<const float4*>(p);
    float4 x1 = *reinterpret_cast<const float4*>(p + 4);
    short8 r;
    r[0] = (short)f2bf(x0.x); r[1] = (short)f2bf(x0.y);
    r[2] = (short)f2bf(x0.z); r[3] = (short)f2bf(x0.w);
    r[4] = (short)f2bf(x1.x); r[5] = (short)f2bf(x1.y);
    r[6] = (short)f2bf(x1.z); r[7] = (short)f2bf(x1.w);
    return r;
}

// ---------------------------------------------------------------------------
// Kernel 1 (proj_mfma_cvt), grid 768 x 256:
//  bid <  512: one 16x16 MFMA proj tile per wave (R18 structure).
//              Q-half -> Eq fp32 [bt][o]; K-half -> EkT16 bf16 [h8][bt][8]
//              via wave-private LDS bounce (256B-contiguous uint4 runs).
//  bid >= 512: K -> K16 bf16 convert (256 blocks x 1024 elems).
// ---------------------------------------------------------------------------
__global__ __launch_bounds__(256) void proj_mfma_cvt_kernel(
    const float* __restrict__ Q, const float* __restrict__ K,
    const float* __restrict__ Wq, const float* __restrict__ Wk,
    float* __restrict__ Eq, unsigned short* __restrict__ EkT16,
    unsigned short* __restrict__ K16)
{
    int bid = blockIdx.x;
    int tid = threadIdx.x;

    if (bid >= 512) {   // ---- K -> bf16 convert ----
        int i = (bid - 512) * 1024 + tid * 4;     // NBT*HH = 262144 elems
        float4 k4 = *reinterpret_cast<const float4*>(K + i);
        ushort4 o4;
        o4.x = f2bf(k4.x); o4.y = f2bf(k4.y); o4.z = f2bf(k4.z); o4.w = f2bf(k4.w);
        *reinterpret_cast<ushort4*>(K16 + i) = o4;
        return;
    }

    __shared__ float bounce[4][16][17];        // per-wave 16x16 tile, pad 17

    int wv = tid >> 6;
    int wid_g = bid * 4 + wv;                  // 0..2047
    int lane = tid & 63;
    int btile = wid_g >> 4;                    // 0..127  (x16 rows)
    int otile = wid_g & 15;                    // 0..15   (x16 outs)
    bool isK = (btile >= 64);
    int bt0 = (btile & 63) * 16;
    int o0 = otile * 16;
    const float* X = isK ? K : Q;
    const float* W = isK ? Wk : Wq;

    int rsel = lane & 15;                      // row-within-16 for A/B frags
    int ksel = (lane >> 4) * 8;                // k-offset within 32

    const float* xp = X + (bt0 + rsel) * HH + ksel;
    const float* wp = W + (o0 + rsel) * HH + ksel;

    f32x4 acc = {0.f, 0.f, 0.f, 0.f};
#pragma unroll 2
    for (int kb = 0; kb < 8; ++kb) {
        short8 a = load_cvt8(xp + kb * 32);
        short8 b = load_cvt8(wp + kb * 32);
        acc = __builtin_amdgcn_mfma_f32_16x16x32_bf16(a, b, acc, 0, 0, 0);
    }

    int rloc = (lane >> 4) * 4;                // C/D local row base
    int cloc = lane & 15;                      // C/D local col
    if (!isK) {
        int o = o0 + cloc;
#pragma unroll
        for (int j = 0; j < 4; ++j) {
            float e = __builtin_amdgcn_exp2f(acc[j] * C2LOG2E);
            Eq[(bt0 + rloc + j) * HH + o] = e;
        }
    } else {
        // stage tile in wave-private LDS (same-wave readback, no barrier)
#pragma unroll
        for (int j = 0; j < 4; ++j)
            bounce[wv][rloc + j][cloc] =
                __builtin_amdgcn_exp2f(acc[j] * C2LOG2E);
        // lanes 0-31: slab sl = lane>>4 (o-block of 8), row r = lane&15.
        // Each lane packs 8 bf16 -> uint4; 16 lanes = 256B contiguous.
        if (lane < 32) {
            int sl = lane >> 4, r = lane & 15;
            unsigned short u0 = f2bf(bounce[wv][r][sl * 8 + 0]);
            unsigned short u1 = f2bf(bounce[wv][r][sl * 8 + 1]);
            unsigned short u2 = f2bf(bounce[wv][r][sl * 8 + 2]);
            unsigned short u3 = f2bf(bounce[wv][r][sl * 8 + 3]);
            unsigned short u4 = f2bf(bounce[wv][r][sl * 8 + 4]);
            unsigned short u5 = f2bf(bounce[wv][r][sl * 8 + 5]);
            unsigned short u6 = f2bf(bounce[wv][r][sl * 8 + 6]);
            unsigned short u7 = f2bf(bounce[wv][r][sl * 8 + 7]);
            uint4 val;
            val.x = (unsigned)u0 | ((unsigned)u1 << 16);
            val.y = (unsigned)u2 | ((unsigned)u3 << 16);
            val.z = (unsigned)u4 | ((unsigned)u5 << 16);
            val.w = (unsigned)u6 | ((unsigned)u7 << 16);
            *reinterpret_cast<uint4*>(
                EkT16 + (((o0 >> 3) + sl) * NBT + bt0 + r) * 8) = val;
        }
    }
}

// ---------------------------------------------------------------------------
// Kernel 2 (attn): R7's bf16 attn VERBATIM (measured ~12us by direct-proj
// subtraction). scores (bf16 EkT16) + sum-only softmax + context (bf16 K16).
// One block per (b,t), 512 threads; block->t permuted for load balance.
// ---------------------------------------------------------------------------
__global__ __launch_bounds__(512, 8) void attn_kernel(
    const float* __restrict__ Eq, const unsigned short* __restrict__ EkT16,
    const unsigned short* __restrict__ K16, const float* __restrict__ v,
    float* __restrict__ ctx, float* __restrict__ alpha)
{
    __shared__ float eq_sh[HH];
    __shared__ float v2_sh[HH];
    __shared__ float al_sh[TT];
    __shared__ float red[8];
    __shared__ float4 cred[8][64];

    int bt = blockIdx.x;
    int b = bt / TT;
    int idx = bt % TT;
    int t = (idx < 256) ? idx : 767 - idx;
    int btr = b * TT + t;
    int tid = threadIdx.x;

    if (tid < HH) {
        eq_sh[tid] = Eq[btr * HH + tid];
        v2_sh[tid] = -2.0f * v[tid];
    }
    __syncthreads();

    // ---- score for s = tid ----
    float sc = 0.f;
    if (tid <= t) {
        const uint4* ek = reinterpret_cast<const uint4*>(EkT16) + (b * TT + tid);
        const float4* q4p = reinterpret_cast<const float4*>(eq_sh);
        const float4* v4p = reinterpret_cast<const float4*>(v2_sh);
#pragma unroll 2
        for (int h8 = 0; h8 < 32; ++h8) {
            uint4 kk = ek[h8 * NBT];             // lanes contiguous: 1KB/wave
            float4 qa = q4p[2 * h8], qb = q4p[2 * h8 + 1];
            float4 va = v4p[2 * h8], vb = v4p[2 * h8 + 1];
            float r0 = __builtin_amdgcn_rcpf(__builtin_fmaf(qa.x, bflo(kk.x), 1.f));
            float r1 = __builtin_amdgcn_rcpf(__builtin_fmaf(qa.y, bfhi(kk.x), 1.f));
            float r2 = __builtin_amdgcn_rcpf(__builtin_fmaf(qa.z, bflo(kk.y), 1.f));
            float r3 = __builtin_amdgcn_rcpf(__builtin_fmaf(qa.w, bfhi(kk.y), 1.f));
            float r4 = __builtin_amdgcn_rcpf(__builtin_fmaf(qb.x, bflo(kk.z), 1.f));
            float r5 = __builtin_amdgcn_rcpf(__builtin_fmaf(qb.y, bfhi(kk.z), 1.f));
            float r6 = __builtin_amdgcn_rcpf(__builtin_fmaf(qb.z, bflo(kk.w), 1.f));
            float r7 = __builtin_amdgcn_rcpf(__builtin_fmaf(qb.w, bfhi(kk.w), 1.f));
            sc = __builtin_fmaf(va.x, r0, sc);
            sc = __builtin_fmaf(va.y, r1, sc);
            sc = __builtin_fmaf(va.z, r2, sc);
            sc = __builtin_fmaf(va.w, r3, sc);
            sc = __builtin_fmaf(vb.x, r4, sc);
            sc = __builtin_fmaf(vb.y, r5, sc);
            sc = __builtin_fmaf(vb.z, r6, sc);
            sc = __builtin_fmaf(vb.w, r7, sc);
        }
    }

    // ---- softmax: sum only (scores bounded by 2*sum|v| ~ 26) ----
    float e = (tid <= t) ? __builtin_amdgcn_exp2f(sc * LOG2E) : 0.f;
    float ssum = e;
#pragma unroll
    for (int off = 32; off > 0; off >>= 1)
        ssum += __shfl_xor(ssum, off);
    if ((tid & 63) == 0) red[tid >> 6] = ssum;
    __syncthreads();
    float denom = (red[0] + red[1]) + (red[2] + red[3])
                + (red[4] + red[5]) + (red[6] + red[7]);
    float a0 = e * __builtin_amdgcn_rcpf(denom);

    al_sh[tid] = a0;
    alpha[btr * TT + tid] = a0;
    __syncthreads();

    // ---- context: hc = tid&63 (4 channels), sg = tid>>6 (s-stride 8) ----
    int hc = tid & 63, sg = tid >> 6;
    const uint2* kb = reinterpret_cast<const uint2*>(K16 + b * TT * HH);
    float4 acc4 = {0.f, 0.f, 0.f, 0.f};
    for (int s = sg; s <= t; s += 8) {
        uint2 kk = kb[s * 64 + hc];              // 8B/lane, coalesced
        float al = al_sh[s];                     // wave-uniform broadcast
        acc4.x = __builtin_fmaf(al, bflo(kk.x), acc4.x);
        acc4.y = __builtin_fmaf(al, bfhi(kk.x), acc4.y);
        acc4.z = __builtin_fmaf(al, bflo(kk.y), acc4.z);
        acc4.w = __builtin_fmaf(al, bfhi(kk.y), acc4.w);
    }
    cred[sg][hc] = acc4;
    __syncthreads();
    if (sg == 0) {
        float4 out = {0.f, 0.f, 0.f, 0.f};
#pragma unroll
        for (int g = 0; g < 8; ++g) {
            float4 c = cred[g][hc];
            out.x += c.x; out.y += c.y; out.z += c.z; out.w += c.w;
        }
        reinterpret_cast<float4*>(ctx + btr * HH)[hc] = out;
    }
}

extern "C" void kernel_launch(void* const* d_in, const int* in_sizes, int n_in,
                              void* d_out, int out_size, void* d_ws, size_t ws_size,
                              hipStream_t stream) {
    const float* Q  = (const float*)d_in[0];
    const float* K  = (const float*)d_in[1];
    const float* Wq = (const float*)d_in[2];
    const float* Wk = (const float*)d_in[3];
    const float* v  = (const float*)d_in[4];

    float* ctx   = (float*)d_out;                      // B*T*H
    float* alpha = (float*)d_out + NBT * HH;           // B*T*T

    // ws: Eq fp32 | EkT16 bf16 | K16 bf16
    float* Eq = (float*)d_ws;                                  // 1 MB
    unsigned short* EkT16 = (unsigned short*)(Eq + NBT * HH);  // 512 KB
    unsigned short* K16   = EkT16 + NBT * HH;                  // 512 KB

    proj_mfma_cvt_kernel<<<768, 256, 0, stream>>>(Q, K, Wq, Wk, Eq, EkT16, K16);
    attn_kernel<<<NBT, 512, 0, stream>>>(Eq, EkT16, K16, v, ctx, alpha);
}